// Round 10
// baseline (275.313 us; speedup 1.0000x reference)
//
#include <hip/hip_runtime.h>

#define S_LEN 2048
#define D_MODEL 1024
#define NHEAD 16
#define HDIM 64
#define BATCH 2
#define M_ROWS (BATCH * S_LEN)   // 4096
#define N_QKV (3 * D_MODEL)      // 3072
#define QSCALE 0.18033688011112042f  // 0.125 * log2(e)
#define MERGE_MAGIC 0x5A17C0DEu

typedef __attribute__((ext_vector_type(8))) short bf16x8;
typedef __attribute__((ext_vector_type(4))) short bf16x4;
typedef __attribute__((ext_vector_type(4))) float f32x4;

#if __has_builtin(__builtin_amdgcn_mfma_f32_16x16x16bf16_1k)
#define MFMA1616(A, B, C) __builtin_amdgcn_mfma_f32_16x16x16bf16_1k((A), (B), (C), 0, 0, 0)
#else
static __device__ __forceinline__ f32x4 mfma1616_asm(bf16x4 a, bf16x4 b, f32x4 c) {
  asm("v_mfma_f32_16x16x16_bf16 %0, %1, %2, %0" : "+v"(c) : "v"(a), "v"(b));
  return c;
}
#define MFMA1616(A, B, C) mfma1616_asm((A), (B), (C))
#endif

static __device__ __forceinline__ unsigned short f2bf(float f) {
  unsigned int u = __float_as_uint(f);
  u += 0x7FFFu + ((u >> 16) & 1u);   // RNE
  return (unsigned short)(u >> 16);
}
// single-instruction packed f32x2 -> bf16x2 (low = a, high = b), RNE
static __device__ __forceinline__ unsigned int cvtpk(float a, float b) {
  unsigned int r;
  asm("v_cvt_pk_bf16_f32 %0, %1, %2" : "=v"(r) : "v"(a), "v"(b));
  return r;
}

// async global->LDS 16B copy; effective LDS dst = wave-uniform base + lane*16
static __device__ __forceinline__ void async_cp16(unsigned short* lds, const unsigned short* g) {
  __builtin_amdgcn_global_load_lds((__attribute__((address_space(1))) void*)g,
                                   (__attribute__((address_space(3))) void*)lds, 16, 0, 0);
}

// ---------------- merged prep: cast x (32B/thread), transpose-cast both weights ----------------
__global__ __launch_bounds__(256) void k_prep(const float* __restrict__ x,
                                              unsigned short* __restrict__ xb,
                                              const float* __restrict__ w_attn,
                                              unsigned short* __restrict__ wqkvT,
                                              const float* __restrict__ w_proj,
                                              unsigned short* __restrict__ wprojT) {
  __shared__ unsigned short T[32][33];
  const int blk = blockIdx.x;
  const int tid = threadIdx.x;
  if (blk < 2048) {
    // x-cast: 2 float4 in, 1 uint4 (4x v_cvt_pk_bf16_f32) out per thread
    int i = blk * 256 + tid;
    float4 v0 = ((const float4*)x)[2 * i];
    float4 v1 = ((const float4*)x)[2 * i + 1];
    uint4 o;
    o.x = cvtpk(v0.x, v0.y);
    o.y = cvtpk(v0.z, v0.w);
    o.z = cvtpk(v1.x, v1.y);
    o.w = cvtpk(v1.z, v1.w);
    ((uint4*)xb)[i] = o;
    return;
  }
  const float* w;
  unsigned short* wT;
  int bid, Ndim;
  if (blk < 5120) { bid = blk - 2048; w = w_attn; wT = wqkvT; Ndim = N_QKV; }
  else            { bid = blk - 5120; w = w_proj; wT = wprojT; Ndim = D_MODEL; }
  const int nb = Ndim / 32;
  const int n0 = (bid % nb) * 32, k0 = (bid / nb) * 32;
  const int tx = tid & 31, ty = tid >> 5;
#pragma unroll
  for (int j = 0; j < 4; ++j) {
    int r = ty + j * 8;
    T[r][tx] = f2bf(w[(size_t)(k0 + r) * Ndim + n0 + tx]);
  }
  __syncthreads();
#pragma unroll
  for (int j = 0; j < 4; ++j) {
    int r = ty + j * 8;
    wT[(size_t)(n0 + r) * D_MODEL + k0 + tx] = T[tx][r];
  }
}

// ---------------- QKV GEMM: [4096,1024] x [1024,3072] + bias (r10 version) ----------------
// V^T stored directly (scatter absorbed by L2 write-combining — r13 measured);
// half-swap (s^4 when d&8) makes attn's b64 V reads phase-conflict-free.
__global__ __launch_bounds__(256) void k_gemm_qkv(const unsigned short* __restrict__ A,
                                                  const unsigned short* __restrict__ Bt,
                                                  const float* __restrict__ bias,
                                                  unsigned short* __restrict__ Qb,
                                                  unsigned short* __restrict__ Kbuf,
                                                  unsigned short* __restrict__ VTb) {
  __shared__ __align__(16) unsigned short As[2][128 * 32];
  __shared__ __align__(16) unsigned short Bs[2][128 * 32];
  const int tid = threadIdx.x;
  const int wid = tid >> 6, lane = tid & 63;
  const int lr = lane & 15, lg = lane >> 4;
  const int blk = blockIdx.x;
  const int xcd = blk & 7, idx = blk >> 3;
  const int bm = ((xcd & 3) * 8 + (idx & 7)) * 128;
  const int bn = ((xcd >> 2) * 12 + (idx >> 3)) * 128;
  const int wm = (wid >> 1) * 64, wn = (wid & 1) * 64;
  const int K = D_MODEL;
  const int c0 = tid, c1 = tid + 256;
  const size_t a0o = (size_t)(bm + (c0 >> 2)) * K + (c0 & 3) * 8;
  const size_t a1o = (size_t)(bm + (c1 >> 2)) * K + (c1 & 3) * 8;
  const size_t b0o = (size_t)(bn + (c0 >> 2)) * K + (c0 & 3) * 8;
  const size_t b1o = (size_t)(bn + (c1 >> 2)) * K + (c1 & 3) * 8;

  f32x4 acc[4][4] = {};

  async_cp16(&As[0][c0 * 8], &A[a0o]);
  async_cp16(&As[0][c1 * 8], &A[a1o]);
  async_cp16(&Bs[0][c0 * 8], &Bt[b0o]);
  async_cp16(&Bs[0][c1 * 8], &Bt[b1o]);

  for (int k0 = 0; k0 < K; k0 += 32) {
    const int p = (k0 >> 5) & 1;
    __syncthreads();
    if (k0 + 32 < K) {
      async_cp16(&As[p ^ 1][c0 * 8], &A[a0o + k0 + 32]);
      async_cp16(&As[p ^ 1][c1 * 8], &A[a1o + k0 + 32]);
      async_cp16(&Bs[p ^ 1][c0 * 8], &Bt[b0o + k0 + 32]);
      async_cp16(&Bs[p ^ 1][c1 * 8], &Bt[b1o + k0 + 32]);
    }
    bf16x8 af[4], bfr[4];
#pragma unroll
    for (int i = 0; i < 4; ++i) af[i] = *(const bf16x8*)&As[p][(wm + i * 16 + lr) * 32 + lg * 8];
#pragma unroll
    for (int t = 0; t < 4; ++t) bfr[t] = *(const bf16x8*)&Bs[p][(wn + t * 16 + lr) * 32 + lg * 8];
#pragma unroll
    for (int i = 0; i < 4; ++i)
#pragma unroll
      for (int t = 0; t < 4; ++t)
        acc[i][t] = __builtin_amdgcn_mfma_f32_16x16x32_bf16(af[i], bfr[t], acc[i][t], 0, 0, 0);
  }
#pragma unroll
  for (int i = 0; i < 4; ++i) {
#pragma unroll
    for (int t = 0; t < 4; ++t) {
      int n = bn + wn + t * 16 + lr;
      int part = n >> 10, rem = n & 1023;
      int h = rem >> 6, d = rem & 63;
      float bv = bias[n];
      int row0 = bm + wm + i * 16 + lg * 4;
      int bb = row0 >> 11, s0 = row0 & 2047;
      if (part == 2) {
        ushort4 vv;
        vv.x = f2bf(acc[i][t][0] + bv);
        vv.y = f2bf(acc[i][t][1] + bv);
        vv.z = f2bf(acc[i][t][2] + bv);
        vv.w = f2bf(acc[i][t][3] + bv);
        int s0x = s0 ^ ((d & 8) ? 4 : 0);   // half-swap for conflict-free attn reads
        *(ushort4*)&VTb[(((size_t)(bb << 4) + h) * HDIM + d) * S_LEN + s0x] = vv;
      } else {
        unsigned short* dst = (part == 0) ? Qb : Kbuf;
        float sc = (part == 0) ? QSCALE : 1.0f;
#pragma unroll
        for (int r = 0; r < 4; ++r)
          dst[(((size_t)(bb << 4) + h) * S_LEN + (s0 + r)) * HDIM + d] = f2bf((acc[i][t][r] + bv) * sc);
      }
    }
  }
}

// ---------------- Proj GEMM: [4096,1024] x [1024,1024] + bias -> fp32 (r14-exact) ----------------
__global__ __launch_bounds__(256) void k_gemm_proj(const unsigned short* __restrict__ A,
                                                   const unsigned short* __restrict__ Bt,
                                                   const float* __restrict__ bias,
                                                   float* __restrict__ out) {
  __shared__ __align__(16) unsigned short As[2][128 * 32];
  __shared__ __align__(16) unsigned short Bs[2][128 * 32];
  const int tid = threadIdx.x;
  const int wid = tid >> 6, lane = tid & 63;
  const int lr = lane & 15, lg = lane >> 4;
  const int blk = blockIdx.x;
  const int xcd = blk & 7, idx = blk >> 3;
  const int bm = (xcd * 4 + (idx & 3)) * 128;
  const int bn = (idx >> 2) * 128;
  const int wm = (wid >> 1) * 64, wn = (wid & 1) * 64;
  const int K = D_MODEL;
  const int c0 = tid, c1 = tid + 256;
  const size_t a0o = (size_t)(bm + (c0 >> 2)) * K + (c0 & 3) * 8;
  const size_t a1o = (size_t)(bm + (c1 >> 2)) * K + (c1 & 3) * 8;
  const size_t b0o = (size_t)(bn + (c0 >> 2)) * K + (c0 & 3) * 8;
  const size_t b1o = (size_t)(bn + (c1 >> 2)) * K + (c1 & 3) * 8;

  f32x4 acc[4][4] = {};

  async_cp16(&As[0][c0 * 8], &A[a0o]);
  async_cp16(&As[0][c1 * 8], &A[a1o]);
  async_cp16(&Bs[0][c0 * 8], &Bt[b0o]);
  async_cp16(&Bs[0][c1 * 8], &Bt[b1o]);

  for (int k0 = 0; k0 < K; k0 += 32) {
    const int p = (k0 >> 5) & 1;
    __syncthreads();
    if (k0 + 32 < K) {
      async_cp16(&As[p ^ 1][c0 * 8], &A[a0o + k0 + 32]);
      async_cp16(&As[p ^ 1][c1 * 8], &A[a1o + k0 + 32]);
      async_cp16(&Bs[p ^ 1][c0 * 8], &Bt[b0o + k0 + 32]);
      async_cp16(&Bs[p ^ 1][c1 * 8], &Bt[b1o + k0 + 32]);
    }
    bf16x8 af[4], bfr[4];
#pragma unroll
    for (int i = 0; i < 4; ++i) af[i] = *(const bf16x8*)&As[p][(wm + i * 16 + lr) * 32 + lg * 8];
#pragma unroll
    for (int t = 0; t < 4; ++t) bfr[t] = *(const bf16x8*)&Bs[p][(wn + t * 16 + lr) * 32 + lg * 8];
#pragma unroll
    for (int i = 0; i < 4; ++i)
#pragma unroll
      for (int t = 0; t < 4; ++t)
        acc[i][t] = __builtin_amdgcn_mfma_f32_16x16x32_bf16(af[i], bfr[t], acc[i][t], 0, 0, 0);
  }
#pragma unroll
  for (int i = 0; i < 4; ++i) {
#pragma unroll
    for (int t = 0; t < 4; ++t) {
      int n = bn + wn + t * 16 + lr;
      float bv = bias[n];
#pragma unroll
      for (int r = 0; r < 4; ++r) {
        int row = bm + wm + i * 16 + lg * 4 + r;
        out[(size_t)row * D_MODEL + n] = acc[i][t][r] + bv;
      }
    }
  }
}

// ---------------- Flash attention round 17: r14 loop + in-kernel last-finisher merge ----------------
// Grid 768 = all blocks co-resident (3/CU). The two chunks of each split strip
// run concurrently; after writing its partial each split block does
// threadfence + atomicExch(flag, MAGIC). The second finisher (old==MAGIC)
// re-reads only the OTHER partial (own still in registers), sums (fixed-m ->
// pure sum), normalizes, writes AO. Removes the k_combine launch + halves
// the merge read traffic. MAGIC-exch is robust to un-zeroed ws and self-resets.
__global__ __launch_bounds__(256, 3) void k_attn17(const unsigned short* __restrict__ Qb,
                                                   const unsigned short* __restrict__ Kb,
                                                   const unsigned short* __restrict__ VT,
                                                   unsigned short* __restrict__ AO,
                                                   float* __restrict__ Pp,
                                                   unsigned int* __restrict__ flags) {
  const int tid = threadIdx.x;
  const int wid = tid >> 6, lane = tid & 63;
  const int lr = lane & 15, quad = lane >> 4;
  const int blk = blockIdx.x;
  const int bh = blk & 31;
  const int id = blk >> 5;                      // 0..23, LPT-ordered
  const int b = bh >> 4, h = bh & 15;

  int T, c;
  if (id < 9)       { T = 7 + id; c = 0; }
  else if (id == 9) { T = 15;     c = 1; }
  else {
    const int j = id - 10, p_ = j >> 1;
    if (j & 1) { T = 14 - p_; c = 1; }
    else       { T = 6 - p_;  c = 0; }
  }
  const int kt0 = c << 4;
  const int tiles = 2 * T + 2;
  const int ktend = (c == 0) ? (tiles < 16 ? tiles : 16) : tiles;

  __shared__ __align__(16) unsigned short Ks[2][64 * 64];
  __shared__ __align__(16) unsigned short Vs[2][64 * 64];

  const unsigned short* Kbh = Kb + (size_t)bh * S_LEN * HDIM;
  const unsigned short* VTbh = VT + (size_t)bh * HDIM * S_LEN;

  const int R0 = T * 128 + wid * 32;            // wave's first q row

  bf16x8 qf[2][2];
#pragma unroll
  for (int st = 0; st < 2; ++st)
#pragma unroll
    for (int dh = 0; dh < 2; ++dh)
      qf[st][dh] = *(const bf16x8*)&Qb[((size_t)bh * S_LEN + R0 + st * 16 + lr) * HDIM + dh * 32 + quad * 8];

  f32x4 Ot[2][4] = {};
  float ls[2] = {0.f, 0.f};

  const int srow = lane >> 3;                   // 0..7
  const int scol = ((lane & 7) ^ srow) * 8;     // xor-swizzled 16B block

  // prologue: stage tile kt0 into buffer 0 (kt0 even -> parity 0)
  {
    const int kg0 = kt0 * 64;
#pragma unroll
    for (int j = 0; j < 2; ++j) {
      const int r0 = wid * 16 + j * 8;
      async_cp16(&Ks[0][r0 * 64 + lane * 8], &Kbh[(size_t)(kg0 + r0 + srow) * HDIM + scol]);
      async_cp16(&Vs[0][r0 * 64 + lane * 8], &VTbh[(size_t)(r0 + srow) * S_LEN + kg0 + scol]);
    }
  }

  for (int kt = kt0; kt < ktend; ++kt) {
    const int k0 = kt * 64;
    const int p = kt & 1;
    __syncthreads();   // drains buf[p] staging; all waves done reading buf[p^1]
    if (kt + 1 < ktend) {
      const int kn = k0 + 64;
#pragma unroll
      for (int j = 0; j < 2; ++j) {
        const int r0 = wid * 16 + j * 8;
        async_cp16(&Ks[p ^ 1][r0 * 64 + lane * 8], &Kbh[(size_t)(kn + r0 + srow) * HDIM + scol]);
        async_cp16(&Vs[p ^ 1][r0 * 64 + lane * 8], &VTbh[(size_t)(r0 + srow) * S_LEN + kn + scol]);
      }
    }
    if (k0 > R0 + 31) continue;                 // both strips done (wave-uniform)

    // K fragments: read ONCE, used by both strips
    bf16x8 kf[4][2];
#pragma unroll
    for (int kg = 0; kg < 4; ++kg)
#pragma unroll
      for (int dh = 0; dh < 2; ++dh)
        kf[kg][dh] = *(const bf16x8*)&Ks[p][(kg * 16 + lr) * 64 + (((dh * 4 + quad) ^ (lr & 7)) * 8)];

    // QK^T + exp for both strips; pf kept per strip
    bf16x4 pf[2][4];
    bool act[2];
#pragma unroll
    for (int st = 0; st < 2; ++st) {
      const int R = R0 + st * 16;
      act[st] = (k0 <= R + 15);
      if (!act[st]) continue;                   // strip finished (wave-uniform)
      f32x4 Sv[4];
      __builtin_amdgcn_s_setprio(1);
#pragma unroll
      for (int kg = 0; kg < 4; ++kg) {
        f32x4 a = {};
        a = __builtin_amdgcn_mfma_f32_16x16x32_bf16(kf[kg][0], qf[st][0], a, 0, 0, 0);
        a = __builtin_amdgcn_mfma_f32_16x16x32_bf16(kf[kg][1], qf[st][1], a, 0, 0, 0);
        Sv[kg] = a;
      }
      __builtin_amdgcn_s_setprio(0);
      if (k0 + 63 > R) {                        // diagonal tile: causal mask
        const int q = R + lr;
#pragma unroll
        for (int kg = 0; kg < 4; ++kg)
#pragma unroll
          for (int r = 0; r < 4; ++r)
            if (k0 + kg * 16 + quad * 4 + r > q) Sv[kg][r] = -1e30f;
      }
      // fixed m=0: P = exp2(S)
      float rs = ls[st];
#pragma unroll
      for (int kg = 0; kg < 4; ++kg) {
        float e0 = __builtin_amdgcn_exp2f(Sv[kg][0]);
        float e1 = __builtin_amdgcn_exp2f(Sv[kg][1]);
        float e2 = __builtin_amdgcn_exp2f(Sv[kg][2]);
        float e3 = __builtin_amdgcn_exp2f(Sv[kg][3]);
        rs += (e0 + e1) + (e2 + e3);
        union { bf16x4 v; unsigned int u[2]; } pu;
        pu.u[0] = cvtpk(e0, e1);
        pu.u[1] = cvtpk(e2, e3);
        pf[st][kg] = pu.v;
      }
      ls[st] = rs;
    }

    // PV: V fragments read ONCE per dg, used by both strips
    __builtin_amdgcn_s_setprio(1);
#pragma unroll
    for (int dg = 0; dg < 4; ++dg) {
      bf16x4 vf[4];
#pragma unroll
      for (int kg = 0; kg < 4; ++kg)
        vf[kg] = *(const bf16x4*)&Vs[p][(dg * 16 + lr) * 64 +
                                        (((kg * 2 + (quad >> 1)) ^ (lr & 7)) * 8) +
                                        (((quad & 1) ^ ((lr >> 3) & 1)) * 4)];
#pragma unroll
      for (int st = 0; st < 2; ++st) {
        if (!act[st]) continue;
#pragma unroll
        for (int kg = 0; kg < 4; ++kg)
          Ot[st][dg] = MFMA1616(vf[kg], pf[st][kg], Ot[st][dg]);
      }
    }
    __builtin_amdgcn_s_setprio(0);
  }

#pragma unroll
  for (int st = 0; st < 2; ++st) {
    ls[st] += __shfl_xor(ls[st], 16);
    ls[st] += __shfl_xor(ls[st], 32);
  }

  if (T < 8) {
    // single-chunk block: finalize and write AO (rows < 1024 of this bh)
#pragma unroll
    for (int st = 0; st < 2; ++st) {
      const float rl = __builtin_amdgcn_rcpf(ls[st]);
      const int s = R0 + st * 16 + lr;
#pragma unroll
      for (int dg = 0; dg < 4; ++dg) {
        const size_t o = ((size_t)b * S_LEN + s) * D_MODEL + h * 64 + dg * 16 + quad * 4;
        *(unsigned int*)&AO[o]     = cvtpk(Ot[st][dg][0] * rl, Ot[st][dg][1] * rl);
        *(unsigned int*)&AO[o + 2] = cvtpk(Ot[st][dg][2] * rl, Ot[st][dg][3] * rl);
      }
    }
  } else {
    // split block: write partial (unnormalized O + l), fence, last-finisher merges.
#pragma unroll
    for (int st = 0; st < 2; ++st) {
      const int sL = T * 8 + wid * 2 + st;      // global strip 64..127
      float* P = Pp + ((size_t)((bh * 64 + (sL - 64)) * 2 + c)) * (16 * 68) + lr * 68;
#pragma unroll
      for (int dg = 0; dg < 4; ++dg)
        *(f32x4*)&P[dg * 16 + quad * 4] = Ot[st][dg];
      if (quad == 0) P[64] = ls[st];
    }
    __threadfence();                            // partials visible device-wide
    const int fi = (bh << 5) + ((T - 8) << 2) + wid;   // one flag per (bh,T,wid)
    unsigned int old = 0;
    if (lane == 0) old = atomicExch(&flags[fi], MERGE_MAGIC);
    old = __shfl(old, 0);
    if (old == MERGE_MAGIC) {
      // second finisher: merge own registers with the other chunk's partial
      __threadfence();                          // acquire: other partial visible
      if (lane == 0) atomicExch(&flags[fi], 0u);   // reset for next iteration
#pragma unroll
      for (int st = 0; st < 2; ++st) {
        const int sL = T * 8 + wid * 2 + st;
        const float* Po = Pp + ((size_t)((bh * 64 + (sL - 64)) * 2 + (c ^ 1))) * (16 * 68) + lr * 68;
        const float lo = Po[64];
        const float rl = __builtin_amdgcn_rcpf(ls[st] + lo);
        const int s = R0 + st * 16 + lr;
#pragma unroll
        for (int dg = 0; dg < 4; ++dg) {
          f32x4 ov = *(const f32x4*)&Po[dg * 16 + quad * 4];
          const size_t o = ((size_t)b * S_LEN + s) * D_MODEL + h * 64 + dg * 16 + quad * 4;
          *(unsigned int*)&AO[o]     = cvtpk((Ot[st][dg][0] + ov[0]) * rl, (Ot[st][dg][1] + ov[1]) * rl);
          *(unsigned int*)&AO[o + 2] = cvtpk((Ot[st][dg][2] + ov[2]) * rl, (Ot[st][dg][3] + ov[3]) * rl);
        }
      }
    }
  }
}

extern "C" void kernel_launch(void* const* d_in, const int* in_sizes, int n_in,
                              void* d_out, int out_size, void* d_ws, size_t ws_size,
                              hipStream_t stream) {
  const float* x      = (const float*)d_in[0];
  const float* w_attn = (const float*)d_in[1];
  const float* b_attn = (const float*)d_in[2];
  const float* w_proj = (const float*)d_in[3];
  const float* b_proj = (const float*)d_in[4];
  float* out = (float*)d_out;

  unsigned short* ws     = (unsigned short*)d_ws;
  unsigned short* xb     = ws;                                   // 4096x1024
  unsigned short* wqkvT  = xb + (size_t)M_ROWS * D_MODEL;        // 3072x1024
  unsigned short* wprojT = wqkvT + (size_t)N_QKV * D_MODEL;      // 1024x1024
  unsigned short* Qb     = wprojT + (size_t)D_MODEL * D_MODEL;   // [B*H, S, hd] (pre-scaled)
  unsigned short* Kb     = Qb + (size_t)M_ROWS * D_MODEL;        // [B*H, S, hd]
  unsigned short* VT     = Kb + (size_t)M_ROWS * D_MODEL;        // [B*H, hd, S] (half-swapped)
  float* Pp              = (float*)(VT + (size_t)M_ROWS * D_MODEL); // split-K partials, 17.8MB
  unsigned int* flags    = (unsigned int*)(Pp + (size_t)2048 * 2 * 16 * 68); // 1024 merge flags
  unsigned short* AO     = xb;  // reuse: xb dead after QKV GEMM

  k_prep<<<6144, 256, 0, stream>>>(x, xb, w_attn, wqkvT, w_proj, wprojT);
  k_gemm_qkv<<<768, 256, 0, stream>>>(xb, wqkvT, b_attn, Qb, Kb, VT);
  k_attn17<<<768, 256, 0, stream>>>(Qb, Kb, VT, AO, Pp, flags);
  k_gemm_proj<<<256, 256, 0, stream>>>(AO, wprojT, b_proj, out);
}

// Round 11
// 173.251 us; speedup vs baseline: 1.5891x; 1.5891x over previous
//
#include <hip/hip_runtime.h>

#define S_LEN 2048
#define D_MODEL 1024
#define NHEAD 16
#define HDIM 64
#define BATCH 2
#define M_ROWS (BATCH * S_LEN)   // 4096
#define N_QKV (3 * D_MODEL)      // 3072
#define QSCALE 0.18033688011112042f  // 0.125 * log2(e)

typedef __attribute__((ext_vector_type(8))) short bf16x8;
typedef __attribute__((ext_vector_type(4))) short bf16x4;
typedef __attribute__((ext_vector_type(4))) float f32x4;

#if __has_builtin(__builtin_amdgcn_mfma_f32_16x16x16bf16_1k)
#define MFMA1616(A, B, C) __builtin_amdgcn_mfma_f32_16x16x16bf16_1k((A), (B), (C), 0, 0, 0)
#else
static __device__ __forceinline__ f32x4 mfma1616_asm(bf16x4 a, bf16x4 b, f32x4 c) {
  asm("v_mfma_f32_16x16x16_bf16 %0, %1, %2, %0" : "+v"(c) : "v"(a), "v"(b));
  return c;
}
#define MFMA1616(A, B, C) mfma1616_asm((A), (B), (C))
#endif

static __device__ __forceinline__ unsigned short f2bf(float f) {
  unsigned int u = __float_as_uint(f);
  u += 0x7FFFu + ((u >> 16) & 1u);   // RNE
  return (unsigned short)(u >> 16);
}
// pack two floats to bf16x2
static __device__ __forceinline__ unsigned int pkbf(float a, float b) {
  unsigned int ua = __float_as_uint(a) + 0x8000u;
  unsigned int ub = __float_as_uint(b) + 0x8000u;
  return __builtin_amdgcn_perm(ub, ua, 0x07060302u);
}
// single-instruction packed f32x2 -> bf16x2 (low = a, high = b), RNE
static __device__ __forceinline__ unsigned int cvtpk(float a, float b) {
  unsigned int r;
  asm("v_cvt_pk_bf16_f32 %0, %1, %2" : "=v"(r) : "v"(a), "v"(b));
  return r;
}

// async global->LDS 16B copy; effective LDS dst = wave-uniform base + lane*16
static __device__ __forceinline__ void async_cp16(unsigned short* lds, const unsigned short* g) {
  __builtin_amdgcn_global_load_lds((__attribute__((address_space(1))) void*)g,
                                   (__attribute__((address_space(3))) void*)lds, 16, 0, 0);
}

// ---------------- merged prep: cast x (32B/thread), transpose-cast both weights ----------------
__global__ __launch_bounds__(256) void k_prep(const float* __restrict__ x,
                                              unsigned short* __restrict__ xb,
                                              const float* __restrict__ w_attn,
                                              unsigned short* __restrict__ wqkvT,
                                              const float* __restrict__ w_proj,
                                              unsigned short* __restrict__ wprojT) {
  __shared__ unsigned short T[32][33];
  const int blk = blockIdx.x;
  const int tid = threadIdx.x;
  if (blk < 2048) {
    // x-cast: 2 float4 in, 1 uint4 (4x v_cvt_pk_bf16_f32) out per thread
    int i = blk * 256 + tid;
    float4 v0 = ((const float4*)x)[2 * i];
    float4 v1 = ((const float4*)x)[2 * i + 1];
    uint4 o;
    o.x = cvtpk(v0.x, v0.y);
    o.y = cvtpk(v0.z, v0.w);
    o.z = cvtpk(v1.x, v1.y);
    o.w = cvtpk(v1.z, v1.w);
    ((uint4*)xb)[i] = o;
    return;
  }
  const float* w;
  unsigned short* wT;
  int bid, Ndim;
  if (blk < 5120) { bid = blk - 2048; w = w_attn; wT = wqkvT; Ndim = N_QKV; }
  else            { bid = blk - 5120; w = w_proj; wT = wprojT; Ndim = D_MODEL; }
  const int nb = Ndim / 32;
  const int n0 = (bid % nb) * 32, k0 = (bid / nb) * 32;
  const int tx = tid & 31, ty = tid >> 5;
#pragma unroll
  for (int j = 0; j < 4; ++j) {
    int r = ty + j * 8;
    T[r][tx] = f2bf(w[(size_t)(k0 + r) * Ndim + n0 + tx]);
  }
  __syncthreads();
#pragma unroll
  for (int j = 0; j < 4; ++j) {
    int r = ty + j * 8;
    wT[(size_t)(n0 + r) * D_MODEL + k0 + tx] = T[tx][r];
  }
}

// ---------------- QKV GEMM: [4096,1024] x [1024,3072] + bias (r10 version) ----------------
// V^T stored directly (scatter absorbed by L2 write-combining — r13 measured);
// half-swap (s^4 when d&8) makes attn's b64 V reads phase-conflict-free.
__global__ __launch_bounds__(256) void k_gemm_qkv(const unsigned short* __restrict__ A,
                                                  const unsigned short* __restrict__ Bt,
                                                  const float* __restrict__ bias,
                                                  unsigned short* __restrict__ Qb,
                                                  unsigned short* __restrict__ Kbuf,
                                                  unsigned short* __restrict__ VTb) {
  __shared__ __align__(16) unsigned short As[2][128 * 32];
  __shared__ __align__(16) unsigned short Bs[2][128 * 32];
  const int tid = threadIdx.x;
  const int wid = tid >> 6, lane = tid & 63;
  const int lr = lane & 15, lg = lane >> 4;
  const int blk = blockIdx.x;
  const int xcd = blk & 7, idx = blk >> 3;
  const int bm = ((xcd & 3) * 8 + (idx & 7)) * 128;
  const int bn = ((xcd >> 2) * 12 + (idx >> 3)) * 128;
  const int wm = (wid >> 1) * 64, wn = (wid & 1) * 64;
  const int K = D_MODEL;
  const int c0 = tid, c1 = tid + 256;
  const size_t a0o = (size_t)(bm + (c0 >> 2)) * K + (c0 & 3) * 8;
  const size_t a1o = (size_t)(bm + (c1 >> 2)) * K + (c1 & 3) * 8;
  const size_t b0o = (size_t)(bn + (c0 >> 2)) * K + (c0 & 3) * 8;
  const size_t b1o = (size_t)(bn + (c1 >> 2)) * K + (c1 & 3) * 8;

  f32x4 acc[4][4] = {};

  async_cp16(&As[0][c0 * 8], &A[a0o]);
  async_cp16(&As[0][c1 * 8], &A[a1o]);
  async_cp16(&Bs[0][c0 * 8], &Bt[b0o]);
  async_cp16(&Bs[0][c1 * 8], &Bt[b1o]);

  for (int k0 = 0; k0 < K; k0 += 32) {
    const int p = (k0 >> 5) & 1;
    __syncthreads();
    if (k0 + 32 < K) {
      async_cp16(&As[p ^ 1][c0 * 8], &A[a0o + k0 + 32]);
      async_cp16(&As[p ^ 1][c1 * 8], &A[a1o + k0 + 32]);
      async_cp16(&Bs[p ^ 1][c0 * 8], &Bt[b0o + k0 + 32]);
      async_cp16(&Bs[p ^ 1][c1 * 8], &Bt[b1o + k0 + 32]);
    }
    bf16x8 af[4], bfr[4];
#pragma unroll
    for (int i = 0; i < 4; ++i) af[i] = *(const bf16x8*)&As[p][(wm + i * 16 + lr) * 32 + lg * 8];
#pragma unroll
    for (int t = 0; t < 4; ++t) bfr[t] = *(const bf16x8*)&Bs[p][(wn + t * 16 + lr) * 32 + lg * 8];
#pragma unroll
    for (int i = 0; i < 4; ++i)
#pragma unroll
      for (int t = 0; t < 4; ++t)
        acc[i][t] = __builtin_amdgcn_mfma_f32_16x16x32_bf16(af[i], bfr[t], acc[i][t], 0, 0, 0);
  }
#pragma unroll
  for (int i = 0; i < 4; ++i) {
#pragma unroll
    for (int t = 0; t < 4; ++t) {
      int n = bn + wn + t * 16 + lr;
      int part = n >> 10, rem = n & 1023;
      int h = rem >> 6, d = rem & 63;
      float bv = bias[n];
      int row0 = bm + wm + i * 16 + lg * 4;
      int bb = row0 >> 11, s0 = row0 & 2047;
      if (part == 2) {
        ushort4 vv;
        vv.x = f2bf(acc[i][t][0] + bv);
        vv.y = f2bf(acc[i][t][1] + bv);
        vv.z = f2bf(acc[i][t][2] + bv);
        vv.w = f2bf(acc[i][t][3] + bv);
        int s0x = s0 ^ ((d & 8) ? 4 : 0);   // half-swap for conflict-free attn reads
        *(ushort4*)&VTb[(((size_t)(bb << 4) + h) * HDIM + d) * S_LEN + s0x] = vv;
      } else {
        unsigned short* dst = (part == 0) ? Qb : Kbuf;
        float sc = (part == 0) ? QSCALE : 1.0f;
#pragma unroll
        for (int r = 0; r < 4; ++r)
          dst[(((size_t)(bb << 4) + h) * S_LEN + (s0 + r)) * HDIM + d] = f2bf((acc[i][t][r] + bv) * sc);
      }
    }
  }
}

// ---------------- Proj GEMM: [4096,1024] x [1024,1024] + bias -> fp32 (r14-exact) ----------------
// r15 lesson: 128x64 retile doubled A-panel fetch (+5us) with no drain-hiding
// gain -> proj at 1 block/CU is traffic/MFMA-bound, not drain-bound. 128x128
// is traffic-optimal for this shape; keep it.
__global__ __launch_bounds__(256) void k_gemm_proj(const unsigned short* __restrict__ A,
                                                   const unsigned short* __restrict__ Bt,
                                                   const float* __restrict__ bias,
                                                   float* __restrict__ out) {
  __shared__ __align__(16) unsigned short As[2][128 * 32];
  __shared__ __align__(16) unsigned short Bs[2][128 * 32];
  const int tid = threadIdx.x;
  const int wid = tid >> 6, lane = tid & 63;
  const int lr = lane & 15, lg = lane >> 4;
  const int blk = blockIdx.x;
  const int xcd = blk & 7, idx = blk >> 3;
  const int bm = (xcd * 4 + (idx & 3)) * 128;
  const int bn = (idx >> 2) * 128;
  const int wm = (wid >> 1) * 64, wn = (wid & 1) * 64;
  const int K = D_MODEL;
  const int c0 = tid, c1 = tid + 256;
  const size_t a0o = (size_t)(bm + (c0 >> 2)) * K + (c0 & 3) * 8;
  const size_t a1o = (size_t)(bm + (c1 >> 2)) * K + (c1 & 3) * 8;
  const size_t b0o = (size_t)(bn + (c0 >> 2)) * K + (c0 & 3) * 8;
  const size_t b1o = (size_t)(bn + (c1 >> 2)) * K + (c1 & 3) * 8;

  f32x4 acc[4][4] = {};

  async_cp16(&As[0][c0 * 8], &A[a0o]);
  async_cp16(&As[0][c1 * 8], &A[a1o]);
  async_cp16(&Bs[0][c0 * 8], &Bt[b0o]);
  async_cp16(&Bs[0][c1 * 8], &Bt[b1o]);

  for (int k0 = 0; k0 < K; k0 += 32) {
    const int p = (k0 >> 5) & 1;
    __syncthreads();
    if (k0 + 32 < K) {
      async_cp16(&As[p ^ 1][c0 * 8], &A[a0o + k0 + 32]);
      async_cp16(&As[p ^ 1][c1 * 8], &A[a1o + k0 + 32]);
      async_cp16(&Bs[p ^ 1][c0 * 8], &Bt[b0o + k0 + 32]);
      async_cp16(&Bs[p ^ 1][c1 * 8], &Bt[b1o + k0 + 32]);
    }
    bf16x8 af[4], bfr[4];
#pragma unroll
    for (int i = 0; i < 4; ++i) af[i] = *(const bf16x8*)&As[p][(wm + i * 16 + lr) * 32 + lg * 8];
#pragma unroll
    for (int t = 0; t < 4; ++t) bfr[t] = *(const bf16x8*)&Bs[p][(wn + t * 16 + lr) * 32 + lg * 8];
#pragma unroll
    for (int i = 0; i < 4; ++i)
#pragma unroll
      for (int t = 0; t < 4; ++t)
        acc[i][t] = __builtin_amdgcn_mfma_f32_16x16x32_bf16(af[i], bfr[t], acc[i][t], 0, 0, 0);
  }
#pragma unroll
  for (int i = 0; i < 4; ++i) {
#pragma unroll
    for (int t = 0; t < 4; ++t) {
      int n = bn + wn + t * 16 + lr;
      float bv = bias[n];
#pragma unroll
      for (int r = 0; r < 4; ++r) {
        int row = bm + wm + i * 16 + lg * 4 + r;
        out[(size_t)row * D_MODEL + n] = acc[i][t][r] + bv;
      }
    }
  }
}

// ---------------- Flash attention round 14: 2 adjacent strips per wave (r16-exact) ----------------
__global__ __launch_bounds__(256, 3) void k_attn14(const unsigned short* __restrict__ Qb,
                                                   const unsigned short* __restrict__ Kb,
                                                   const unsigned short* __restrict__ VT,
                                                   unsigned short* __restrict__ AO,
                                                   float* __restrict__ Pp) {
  const int tid = threadIdx.x;
  const int wid = tid >> 6, lane = tid & 63;
  const int lr = lane & 15, quad = lane >> 4;
  const int blk = blockIdx.x;
  const int bh = blk & 31;
  const int id = blk >> 5;                      // 0..23, LPT-ordered
  const int b = bh >> 4, h = bh & 15;

  int T, c;
  if (id < 9)       { T = 7 + id; c = 0; }
  else if (id == 9) { T = 15;     c = 1; }
  else {
    const int j = id - 10, p_ = j >> 1;
    if (j & 1) { T = 14 - p_; c = 1; }
    else       { T = 6 - p_;  c = 0; }
  }
  const int kt0 = c << 4;
  const int tiles = 2 * T + 2;
  const int ktend = (c == 0) ? (tiles < 16 ? tiles : 16) : tiles;

  __shared__ __align__(16) unsigned short Ks[2][64 * 64];
  __shared__ __align__(16) unsigned short Vs[2][64 * 64];

  const unsigned short* Kbh = Kb + (size_t)bh * S_LEN * HDIM;
  const unsigned short* VTbh = VT + (size_t)bh * HDIM * S_LEN;

  const int R0 = T * 128 + wid * 32;            // wave's first q row

  bf16x8 qf[2][2];
#pragma unroll
  for (int st = 0; st < 2; ++st)
#pragma unroll
    for (int dh = 0; dh < 2; ++dh)
      qf[st][dh] = *(const bf16x8*)&Qb[((size_t)bh * S_LEN + R0 + st * 16 + lr) * HDIM + dh * 32 + quad * 8];

  f32x4 Ot[2][4] = {};
  float ls[2] = {0.f, 0.f};

  const int srow = lane >> 3;                   // 0..7
  const int scol = ((lane & 7) ^ srow) * 8;     // xor-swizzled 16B block

  // prologue: stage tile kt0 into buffer 0 (kt0 even -> parity 0)
  {
    const int kg0 = kt0 * 64;
#pragma unroll
    for (int j = 0; j < 2; ++j) {
      const int r0 = wid * 16 + j * 8;
      async_cp16(&Ks[0][r0 * 64 + lane * 8], &Kbh[(size_t)(kg0 + r0 + srow) * HDIM + scol]);
      async_cp16(&Vs[0][r0 * 64 + lane * 8], &VTbh[(size_t)(r0 + srow) * S_LEN + kg0 + scol]);
    }
  }

  for (int kt = kt0; kt < ktend; ++kt) {
    const int k0 = kt * 64;
    const int p = kt & 1;
    __syncthreads();   // drains buf[p] staging; all waves done reading buf[p^1]
    if (kt + 1 < ktend) {
      const int kn = k0 + 64;
#pragma unroll
      for (int j = 0; j < 2; ++j) {
        const int r0 = wid * 16 + j * 8;
        async_cp16(&Ks[p ^ 1][r0 * 64 + lane * 8], &Kbh[(size_t)(kn + r0 + srow) * HDIM + scol]);
        async_cp16(&Vs[p ^ 1][r0 * 64 + lane * 8], &VTbh[(size_t)(r0 + srow) * S_LEN + kn + scol]);
      }
    }
    if (k0 > R0 + 31) continue;                 // both strips done (wave-uniform)

    // K fragments: read ONCE, used by both strips
    bf16x8 kf[4][2];
#pragma unroll
    for (int kg = 0; kg < 4; ++kg)
#pragma unroll
      for (int dh = 0; dh < 2; ++dh)
        kf[kg][dh] = *(const bf16x8*)&Ks[p][(kg * 16 + lr) * 64 + (((dh * 4 + quad) ^ (lr & 7)) * 8)];

    // QK^T + exp for both strips; pf kept per strip
    bf16x4 pf[2][4];
    bool act[2];
#pragma unroll
    for (int st = 0; st < 2; ++st) {
      const int R = R0 + st * 16;
      act[st] = (k0 <= R + 15);
      if (!act[st]) continue;                   // strip finished (wave-uniform)
      f32x4 Sv[4];
      __builtin_amdgcn_s_setprio(1);
#pragma unroll
      for (int kg = 0; kg < 4; ++kg) {
        f32x4 a = {};
        a = __builtin_amdgcn_mfma_f32_16x16x32_bf16(kf[kg][0], qf[st][0], a, 0, 0, 0);
        a = __builtin_amdgcn_mfma_f32_16x16x32_bf16(kf[kg][1], qf[st][1], a, 0, 0, 0);
        Sv[kg] = a;
      }
      __builtin_amdgcn_s_setprio(0);
      if (k0 + 63 > R) {                        // diagonal tile: causal mask
        const int q = R + lr;
#pragma unroll
        for (int kg = 0; kg < 4; ++kg)
#pragma unroll
          for (int r = 0; r < 4; ++r)
            if (k0 + kg * 16 + quad * 4 + r > q) Sv[kg][r] = -1e30f;
      }
      // fixed m=0: P = exp2(S)
      float rs = ls[st];
#pragma unroll
      for (int kg = 0; kg < 4; ++kg) {
        float e0 = __builtin_amdgcn_exp2f(Sv[kg][0]);
        float e1 = __builtin_amdgcn_exp2f(Sv[kg][1]);
        float e2 = __builtin_amdgcn_exp2f(Sv[kg][2]);
        float e3 = __builtin_amdgcn_exp2f(Sv[kg][3]);
        rs += (e0 + e1) + (e2 + e3);
        union { bf16x4 v; unsigned int u[2]; } pu;
        pu.u[0] = cvtpk(e0, e1);
        pu.u[1] = cvtpk(e2, e3);
        pf[st][kg] = pu.v;
      }
      ls[st] = rs;
    }

    // PV: V fragments read ONCE per dg, used by both strips
    __builtin_amdgcn_s_setprio(1);
#pragma unroll
    for (int dg = 0; dg < 4; ++dg) {
      bf16x4 vf[4];
#pragma unroll
      for (int kg = 0; kg < 4; ++kg)
        vf[kg] = *(const bf16x4*)&Vs[p][(dg * 16 + lr) * 64 +
                                        (((kg * 2 + (quad >> 1)) ^ (lr & 7)) * 8) +
                                        (((quad & 1) ^ ((lr >> 3) & 1)) * 4)];
#pragma unroll
      for (int st = 0; st < 2; ++st) {
        if (!act[st]) continue;
#pragma unroll
        for (int kg = 0; kg < 4; ++kg)
          Ot[st][dg] = MFMA1616(vf[kg], pf[st][kg], Ot[st][dg]);
      }
    }
    __builtin_amdgcn_s_setprio(0);
  }

#pragma unroll
  for (int st = 0; st < 2; ++st) {
    ls[st] += __shfl_xor(ls[st], 16);
    ls[st] += __shfl_xor(ls[st], 32);
  }

  if (T < 8) {
    // single-chunk block: finalize and write AO (rows < 1024 of this bh)
#pragma unroll
    for (int st = 0; st < 2; ++st) {
      const float rl = __builtin_amdgcn_rcpf(ls[st]);
      const int s = R0 + st * 16 + lr;
#pragma unroll
      for (int dg = 0; dg < 4; ++dg) {
        const size_t o = ((size_t)b * S_LEN + s) * D_MODEL + h * 64 + dg * 16 + quad * 4;
        *(unsigned int*)&AO[o]     = cvtpk(Ot[st][dg][0] * rl, Ot[st][dg][1] * rl);
        *(unsigned int*)&AO[o + 2] = cvtpk(Ot[st][dg][2] * rl, Ot[st][dg][3] * rl);
      }
    }
  } else {
    // split block: write f32 partials (m=0, l, unnormalized O); k_combine merges.
#pragma unroll
    for (int st = 0; st < 2; ++st) {
      const int sL = T * 8 + wid * 2 + st;      // global strip 64..127
      float* P = Pp + ((size_t)((bh * 64 + (sL - 64)) * 2 + c)) * (16 * 68) + lr * 68;
#pragma unroll
      for (int dg = 0; dg < 4; ++dg)
        *(f32x4*)&P[dg * 16 + quad * 4] = Ot[st][dg];
      if (quad == 0) { P[64] = 0.f; P[65] = ls[st]; }
    }
  }
}

// ---------------- combine: merge the 2 partials of each split strip ----------------
__global__ __launch_bounds__(256) void k_combine(const float* __restrict__ Pp,
                                                 unsigned short* __restrict__ AO) {
  const int lane = threadIdx.x & 63;
  const int sid = blockIdx.x * 4 + (threadIdx.x >> 6);   // 0..2047
  const int bh = sid >> 6, jrel = sid & 63;
  const int b = bh >> 4, h = bh & 15;
  const int r = lane & 15, cg = lane >> 4;
  const float* P0 = Pp + ((size_t)(bh * 64 + jrel) * 2) * (16 * 68) + r * 68;
  const float* P1 = P0 + 16 * 68;
  const float m0 = P0[64], l0 = P0[65];
  const float m1 = P1[64], l1 = P1[65];
  const float M = fmaxf(m0, m1);
  const float w0 = __builtin_amdgcn_exp2f(m0 - M);
  const float w1 = __builtin_amdgcn_exp2f(m1 - M);
  const float rl = __builtin_amdgcn_rcpf(l0 * w0 + l1 * w1);
  const int s = (64 + jrel) * 16 + r;                    // rows 1024..2047
  const size_t o0 = ((size_t)b * S_LEN + s) * D_MODEL + h * 64 + cg * 16;
#pragma unroll
  for (int q4 = 0; q4 < 4; ++q4) {
    f32x4 a = *(const f32x4*)&P0[cg * 16 + q4 * 4];
    f32x4 b4 = *(const f32x4*)&P1[cg * 16 + q4 * 4];
    float o0v = (a[0] * w0 + b4[0] * w1) * rl;
    float o1v = (a[1] * w0 + b4[1] * w1) * rl;
    float o2v = (a[2] * w0 + b4[2] * w1) * rl;
    float o3v = (a[3] * w0 + b4[3] * w1) * rl;
    *(unsigned int*)&AO[o0 + q4 * 4]     = cvtpk(o0v, o1v);
    *(unsigned int*)&AO[o0 + q4 * 4 + 2] = cvtpk(o2v, o3v);
  }
}

extern "C" void kernel_launch(void* const* d_in, const int* in_sizes, int n_in,
                              void* d_out, int out_size, void* d_ws, size_t ws_size,
                              hipStream_t stream) {
  const float* x      = (const float*)d_in[0];
  const float* w_attn = (const float*)d_in[1];
  const float* b_attn = (const float*)d_in[2];
  const float* w_proj = (const float*)d_in[3];
  const float* b_proj = (const float*)d_in[4];
  float* out = (float*)d_out;

  unsigned short* ws     = (unsigned short*)d_ws;
  unsigned short* xb     = ws;                                   // 4096x1024
  unsigned short* wqkvT  = xb + (size_t)M_ROWS * D_MODEL;        // 3072x1024
  unsigned short* wprojT = wqkvT + (size_t)N_QKV * D_MODEL;      // 1024x1024
  unsigned short* Qb     = wprojT + (size_t)D_MODEL * D_MODEL;   // [B*H, S, hd] (pre-scaled)
  unsigned short* Kb     = Qb + (size_t)M_ROWS * D_MODEL;        // [B*H, S, hd]
  unsigned short* VT     = Kb + (size_t)M_ROWS * D_MODEL;        // [B*H, hd, S] (half-swapped)
  float* Pp              = (float*)(VT + (size_t)M_ROWS * D_MODEL); // split-K partials, 17.8MB
  unsigned short* AO     = xb;  // reuse: xb dead after QKV GEMM

  k_prep<<<6144, 256, 0, stream>>>(x, xb, w_attn, wqkvT, w_proj, wprojT);
  k_gemm_qkv<<<768, 256, 0, stream>>>(xb, wqkvT, b_attn, Qb, Kb, VT);
  k_attn14<<<768, 256, 0, stream>>>(Qb, Kb, VT, AO, Pp);
  k_combine<<<512, 256, 0, stream>>>(Pp, AO);
  k_gemm_proj<<<256, 256, 0, stream>>>(AO, wprojT, b_proj, out);
}

// Round 12
// 172.144 us; speedup vs baseline: 1.5993x; 1.0064x over previous
//
#include <hip/hip_runtime.h>

#define S_LEN 2048
#define D_MODEL 1024
#define NHEAD 16
#define HDIM 64
#define BATCH 2
#define M_ROWS (BATCH * S_LEN)   // 4096
#define N_QKV (3 * D_MODEL)      // 3072
#define QSCALE 0.18033688011112042f  // 0.125 * log2(e)

typedef __attribute__((ext_vector_type(8))) short bf16x8;
typedef __attribute__((ext_vector_type(4))) short bf16x4;
typedef __attribute__((ext_vector_type(4))) float f32x4;

#if __has_builtin(__builtin_amdgcn_mfma_f32_16x16x16bf16_1k)
#define MFMA1616(A, B, C) __builtin_amdgcn_mfma_f32_16x16x16bf16_1k((A), (B), (C), 0, 0, 0)
#else
static __device__ __forceinline__ f32x4 mfma1616_asm(bf16x4 a, bf16x4 b, f32x4 c) {
  asm("v_mfma_f32_16x16x16_bf16 %0, %1, %2, %0" : "+v"(c) : "v"(a), "v"(b));
  return c;
}
#define MFMA1616(A, B, C) mfma1616_asm((A), (B), (C))
#endif

static __device__ __forceinline__ unsigned short f2bf(float f) {
  unsigned int u = __float_as_uint(f);
  u += 0x7FFFu + ((u >> 16) & 1u);   // RNE
  return (unsigned short)(u >> 16);
}
// pack two floats to bf16x2
static __device__ __forceinline__ unsigned int pkbf(float a, float b) {
  unsigned int ua = __float_as_uint(a) + 0x8000u;
  unsigned int ub = __float_as_uint(b) + 0x8000u;
  return __builtin_amdgcn_perm(ub, ua, 0x07060302u);
}
// single-instruction packed f32x2 -> bf16x2 (low = a, high = b), RNE
static __device__ __forceinline__ unsigned int cvtpk(float a, float b) {
  unsigned int r;
  asm("v_cvt_pk_bf16_f32 %0, %1, %2" : "=v"(r) : "v"(a), "v"(b));
  return r;
}

// async global->LDS 16B copy; effective LDS dst = wave-uniform base + lane*16
static __device__ __forceinline__ void async_cp16(unsigned short* lds, const unsigned short* g) {
  __builtin_amdgcn_global_load_lds((__attribute__((address_space(1))) void*)g,
                                   (__attribute__((address_space(3))) void*)lds, 16, 0, 0);
}

// ---------------- merged prep: cast x (32B/thread), transpose-cast both weights ----------------
__global__ __launch_bounds__(256) void k_prep(const float* __restrict__ x,
                                              unsigned short* __restrict__ xb,
                                              const float* __restrict__ w_attn,
                                              unsigned short* __restrict__ wqkvT,
                                              const float* __restrict__ w_proj,
                                              unsigned short* __restrict__ wprojT) {
  __shared__ unsigned short T[32][33];
  const int blk = blockIdx.x;
  const int tid = threadIdx.x;
  if (blk < 2048) {
    // x-cast: 2 float4 in, 1 uint4 (4x v_cvt_pk_bf16_f32) out per thread
    int i = blk * 256 + tid;
    float4 v0 = ((const float4*)x)[2 * i];
    float4 v1 = ((const float4*)x)[2 * i + 1];
    uint4 o;
    o.x = cvtpk(v0.x, v0.y);
    o.y = cvtpk(v0.z, v0.w);
    o.z = cvtpk(v1.x, v1.y);
    o.w = cvtpk(v1.z, v1.w);
    ((uint4*)xb)[i] = o;
    return;
  }
  const float* w;
  unsigned short* wT;
  int bid, Ndim;
  if (blk < 5120) { bid = blk - 2048; w = w_attn; wT = wqkvT; Ndim = N_QKV; }
  else            { bid = blk - 5120; w = w_proj; wT = wprojT; Ndim = D_MODEL; }
  const int nb = Ndim / 32;
  const int n0 = (bid % nb) * 32, k0 = (bid / nb) * 32;
  const int tx = tid & 31, ty = tid >> 5;
#pragma unroll
  for (int j = 0; j < 4; ++j) {
    int r = ty + j * 8;
    T[r][tx] = f2bf(w[(size_t)(k0 + r) * Ndim + n0 + tx]);
  }
  __syncthreads();
#pragma unroll
  for (int j = 0; j < 4; ++j) {
    int r = ty + j * 8;
    wT[(size_t)(n0 + r) * D_MODEL + k0 + tx] = T[tx][r];
  }
}

// ---------------- QKV GEMM: [4096,1024] x [1024,3072] + bias (r10 version) ----------------
// V^T stored directly (scatter absorbed by L2 write-combining — r13 measured);
// half-swap (s^4 when d&8) makes attn's b64 V reads phase-conflict-free.
__global__ __launch_bounds__(256) void k_gemm_qkv(const unsigned short* __restrict__ A,
                                                  const unsigned short* __restrict__ Bt,
                                                  const float* __restrict__ bias,
                                                  unsigned short* __restrict__ Qb,
                                                  unsigned short* __restrict__ Kbuf,
                                                  unsigned short* __restrict__ VTb) {
  __shared__ __align__(16) unsigned short As[2][128 * 32];
  __shared__ __align__(16) unsigned short Bs[2][128 * 32];
  const int tid = threadIdx.x;
  const int wid = tid >> 6, lane = tid & 63;
  const int lr = lane & 15, lg = lane >> 4;
  const int blk = blockIdx.x;
  const int xcd = blk & 7, idx = blk >> 3;
  const int bm = ((xcd & 3) * 8 + (idx & 7)) * 128;
  const int bn = ((xcd >> 2) * 12 + (idx >> 3)) * 128;
  const int wm = (wid >> 1) * 64, wn = (wid & 1) * 64;
  const int K = D_MODEL;
  const int c0 = tid, c1 = tid + 256;
  const size_t a0o = (size_t)(bm + (c0 >> 2)) * K + (c0 & 3) * 8;
  const size_t a1o = (size_t)(bm + (c1 >> 2)) * K + (c1 & 3) * 8;
  const size_t b0o = (size_t)(bn + (c0 >> 2)) * K + (c0 & 3) * 8;
  const size_t b1o = (size_t)(bn + (c1 >> 2)) * K + (c1 & 3) * 8;

  f32x4 acc[4][4] = {};

  async_cp16(&As[0][c0 * 8], &A[a0o]);
  async_cp16(&As[0][c1 * 8], &A[a1o]);
  async_cp16(&Bs[0][c0 * 8], &Bt[b0o]);
  async_cp16(&Bs[0][c1 * 8], &Bt[b1o]);

  for (int k0 = 0; k0 < K; k0 += 32) {
    const int p = (k0 >> 5) & 1;
    __syncthreads();
    if (k0 + 32 < K) {
      async_cp16(&As[p ^ 1][c0 * 8], &A[a0o + k0 + 32]);
      async_cp16(&As[p ^ 1][c1 * 8], &A[a1o + k0 + 32]);
      async_cp16(&Bs[p ^ 1][c0 * 8], &Bt[b0o + k0 + 32]);
      async_cp16(&Bs[p ^ 1][c1 * 8], &Bt[b1o + k0 + 32]);
    }
    bf16x8 af[4], bfr[4];
#pragma unroll
    for (int i = 0; i < 4; ++i) af[i] = *(const bf16x8*)&As[p][(wm + i * 16 + lr) * 32 + lg * 8];
#pragma unroll
    for (int t = 0; t < 4; ++t) bfr[t] = *(const bf16x8*)&Bs[p][(wn + t * 16 + lr) * 32 + lg * 8];
#pragma unroll
    for (int i = 0; i < 4; ++i)
#pragma unroll
      for (int t = 0; t < 4; ++t)
        acc[i][t] = __builtin_amdgcn_mfma_f32_16x16x32_bf16(af[i], bfr[t], acc[i][t], 0, 0, 0);
  }
#pragma unroll
  for (int i = 0; i < 4; ++i) {
#pragma unroll
    for (int t = 0; t < 4; ++t) {
      int n = bn + wn + t * 16 + lr;
      int part = n >> 10, rem = n & 1023;
      int h = rem >> 6, d = rem & 63;
      float bv = bias[n];
      int row0 = bm + wm + i * 16 + lg * 4;
      int bb = row0 >> 11, s0 = row0 & 2047;
      if (part == 2) {
        ushort4 vv;
        vv.x = f2bf(acc[i][t][0] + bv);
        vv.y = f2bf(acc[i][t][1] + bv);
        vv.z = f2bf(acc[i][t][2] + bv);
        vv.w = f2bf(acc[i][t][3] + bv);
        int s0x = s0 ^ ((d & 8) ? 4 : 0);   // half-swap for conflict-free attn reads
        *(ushort4*)&VTb[(((size_t)(bb << 4) + h) * HDIM + d) * S_LEN + s0x] = vv;
      } else {
        unsigned short* dst = (part == 0) ? Qb : Kbuf;
        float sc = (part == 0) ? QSCALE : 1.0f;
#pragma unroll
        for (int r = 0; r < 4; ++r)
          dst[(((size_t)(bb << 4) + h) * S_LEN + (s0 + r)) * HDIM + d] = f2bf((acc[i][t][r] + bv) * sc);
      }
    }
  }
}

// ---------------- Proj GEMM: [4096,1024] x [1024,1024] + bias -> fp32 (r14-exact) ----------------
__global__ __launch_bounds__(256) void k_gemm_proj(const unsigned short* __restrict__ A,
                                                   const unsigned short* __restrict__ Bt,
                                                   const float* __restrict__ bias,
                                                   float* __restrict__ out) {
  __shared__ __align__(16) unsigned short As[2][128 * 32];
  __shared__ __align__(16) unsigned short Bs[2][128 * 32];
  const int tid = threadIdx.x;
  const int wid = tid >> 6, lane = tid & 63;
  const int lr = lane & 15, lg = lane >> 4;
  const int blk = blockIdx.x;
  const int xcd = blk & 7, idx = blk >> 3;
  const int bm = (xcd * 4 + (idx & 3)) * 128;
  const int bn = (idx >> 2) * 128;
  const int wm = (wid >> 1) * 64, wn = (wid & 1) * 64;
  const int K = D_MODEL;
  const int c0 = tid, c1 = tid + 256;
  const size_t a0o = (size_t)(bm + (c0 >> 2)) * K + (c0 & 3) * 8;
  const size_t a1o = (size_t)(bm + (c1 >> 2)) * K + (c1 & 3) * 8;
  const size_t b0o = (size_t)(bn + (c0 >> 2)) * K + (c0 & 3) * 8;
  const size_t b1o = (size_t)(bn + (c1 >> 2)) * K + (c1 & 3) * 8;

  f32x4 acc[4][4] = {};

  async_cp16(&As[0][c0 * 8], &A[a0o]);
  async_cp16(&As[0][c1 * 8], &A[a1o]);
  async_cp16(&Bs[0][c0 * 8], &Bt[b0o]);
  async_cp16(&Bs[0][c1 * 8], &Bt[b1o]);

  for (int k0 = 0; k0 < K; k0 += 32) {
    const int p = (k0 >> 5) & 1;
    __syncthreads();
    if (k0 + 32 < K) {
      async_cp16(&As[p ^ 1][c0 * 8], &A[a0o + k0 + 32]);
      async_cp16(&As[p ^ 1][c1 * 8], &A[a1o + k0 + 32]);
      async_cp16(&Bs[p ^ 1][c0 * 8], &Bt[b0o + k0 + 32]);
      async_cp16(&Bs[p ^ 1][c1 * 8], &Bt[b1o + k0 + 32]);
    }
    bf16x8 af[4], bfr[4];
#pragma unroll
    for (int i = 0; i < 4; ++i) af[i] = *(const bf16x8*)&As[p][(wm + i * 16 + lr) * 32 + lg * 8];
#pragma unroll
    for (int t = 0; t < 4; ++t) bfr[t] = *(const bf16x8*)&Bs[p][(wn + t * 16 + lr) * 32 + lg * 8];
#pragma unroll
    for (int i = 0; i < 4; ++i)
#pragma unroll
      for (int t = 0; t < 4; ++t)
        acc[i][t] = __builtin_amdgcn_mfma_f32_16x16x32_bf16(af[i], bfr[t], acc[i][t], 0, 0, 0);
  }
#pragma unroll
  for (int i = 0; i < 4; ++i) {
#pragma unroll
    for (int t = 0; t < 4; ++t) {
      int n = bn + wn + t * 16 + lr;
      float bv = bias[n];
#pragma unroll
      for (int r = 0; r < 4; ++r) {
        int row = bm + wm + i * 16 + lg * 4 + r;
        out[(size_t)row * D_MODEL + n] = acc[i][t][r] + bv;
      }
    }
  }
}

// ---------------- Flash attention round 19: r14 loop + CU-balanced chunk triples ----------------
// Grid 768 = 3 blocks/CU; round-robin puts blocks {i, i+256, i+512} (= id
// triples {t, t+8, t+16}) on one CU. The old LPT map gave triple sums
// {40,40,36,36,32,32,28,28} tile-times -> makespan 40 vs avg 34 (~15% tail
// idle). New id->(T,c) table packs exact-34 triples: two {16,16,2} and six
// {16,a,b} with a+b=18. Coverage of all 24 (T,c) chunks verified by
// enumeration. Everything else byte-identical to r16.
__global__ __launch_bounds__(256, 3) void k_attn19(const unsigned short* __restrict__ Qb,
                                                   const unsigned short* __restrict__ Kb,
                                                   const unsigned short* __restrict__ VT,
                                                   unsigned short* __restrict__ AO,
                                                   float* __restrict__ Pp) {
  const int tid = threadIdx.x;
  const int wid = tid >> 6, lane = tid & 63;
  const int lr = lane & 15, quad = lane >> 4;
  const int blk = blockIdx.x;
  const int bh = blk & 31;
  const int id = blk >> 5;                      // 0..23
  const int b = bh >> 4, h = bh & 15;

  // CU-balanced map: triple t = ids {t, t+8, t+16}, each sums to 34 tiles.
  // durs: ids0-7 = 16,16,16,16,16,16,16,16 ; ids8-15 = 16,16,14,14,12,12,10,10 ;
  //       ids16-23 = 2,2,4,4,6,6,8,8
  const unsigned char Tmap[24] = {7, 9, 11, 12, 13, 14, 15, 15,
                                  8, 10, 6, 14, 5, 13, 4, 12,
                                  0, 8, 1, 9, 2, 10, 3, 11};
  const int T = Tmap[id];
  const int c = (0xAAA880u >> id) & 1;          // c=1 ids: 7,11,13,15,17,19,21,23

  const int kt0 = c << 4;
  const int tiles = 2 * T + 2;
  const int ktend = (c == 0) ? (tiles < 16 ? tiles : 16) : tiles;

  __shared__ __align__(16) unsigned short Ks[2][64 * 64];
  __shared__ __align__(16) unsigned short Vs[2][64 * 64];

  const unsigned short* Kbh = Kb + (size_t)bh * S_LEN * HDIM;
  const unsigned short* VTbh = VT + (size_t)bh * HDIM * S_LEN;

  const int R0 = T * 128 + wid * 32;            // wave's first q row

  bf16x8 qf[2][2];
#pragma unroll
  for (int st = 0; st < 2; ++st)
#pragma unroll
    for (int dh = 0; dh < 2; ++dh)
      qf[st][dh] = *(const bf16x8*)&Qb[((size_t)bh * S_LEN + R0 + st * 16 + lr) * HDIM + dh * 32 + quad * 8];

  f32x4 Ot[2][4] = {};
  float ls[2] = {0.f, 0.f};

  const int srow = lane >> 3;                   // 0..7
  const int scol = ((lane & 7) ^ srow) * 8;     // xor-swizzled 16B block

  // prologue: stage tile kt0 into buffer 0 (kt0 even -> parity 0)
  {
    const int kg0 = kt0 * 64;
#pragma unroll
    for (int j = 0; j < 2; ++j) {
      const int r0 = wid * 16 + j * 8;
      async_cp16(&Ks[0][r0 * 64 + lane * 8], &Kbh[(size_t)(kg0 + r0 + srow) * HDIM + scol]);
      async_cp16(&Vs[0][r0 * 64 + lane * 8], &VTbh[(size_t)(r0 + srow) * S_LEN + kg0 + scol]);
    }
  }

  for (int kt = kt0; kt < ktend; ++kt) {
    const int k0 = kt * 64;
    const int p = kt & 1;
    __syncthreads();   // drains buf[p] staging; all waves done reading buf[p^1]
    if (kt + 1 < ktend) {
      const int kn = k0 + 64;
#pragma unroll
      for (int j = 0; j < 2; ++j) {
        const int r0 = wid * 16 + j * 8;
        async_cp16(&Ks[p ^ 1][r0 * 64 + lane * 8], &Kbh[(size_t)(kn + r0 + srow) * HDIM + scol]);
        async_cp16(&Vs[p ^ 1][r0 * 64 + lane * 8], &VTbh[(size_t)(r0 + srow) * S_LEN + kn + scol]);
      }
    }
    if (k0 > R0 + 31) continue;                 // both strips done (wave-uniform)

    // K fragments: read ONCE, used by both strips
    bf16x8 kf[4][2];
#pragma unroll
    for (int kg = 0; kg < 4; ++kg)
#pragma unroll
      for (int dh = 0; dh < 2; ++dh)
        kf[kg][dh] = *(const bf16x8*)&Ks[p][(kg * 16 + lr) * 64 + (((dh * 4 + quad) ^ (lr & 7)) * 8)];

    // QK^T + exp for both strips; pf kept per strip
    bf16x4 pf[2][4];
    bool act[2];
#pragma unroll
    for (int st = 0; st < 2; ++st) {
      const int R = R0 + st * 16;
      act[st] = (k0 <= R + 15);
      if (!act[st]) continue;                   // strip finished (wave-uniform)
      f32x4 Sv[4];
      __builtin_amdgcn_s_setprio(1);
#pragma unroll
      for (int kg = 0; kg < 4; ++kg) {
        f32x4 a = {};
        a = __builtin_amdgcn_mfma_f32_16x16x32_bf16(kf[kg][0], qf[st][0], a, 0, 0, 0);
        a = __builtin_amdgcn_mfma_f32_16x16x32_bf16(kf[kg][1], qf[st][1], a, 0, 0, 0);
        Sv[kg] = a;
      }
      __builtin_amdgcn_s_setprio(0);
      if (k0 + 63 > R) {                        // diagonal tile: causal mask
        const int q = R + lr;
#pragma unroll
        for (int kg = 0; kg < 4; ++kg)
#pragma unroll
          for (int r = 0; r < 4; ++r)
            if (k0 + kg * 16 + quad * 4 + r > q) Sv[kg][r] = -1e30f;
      }
      // fixed m=0: P = exp2(S)
      float rs = ls[st];
#pragma unroll
      for (int kg = 0; kg < 4; ++kg) {
        float e0 = __builtin_amdgcn_exp2f(Sv[kg][0]);
        float e1 = __builtin_amdgcn_exp2f(Sv[kg][1]);
        float e2 = __builtin_amdgcn_exp2f(Sv[kg][2]);
        float e3 = __builtin_amdgcn_exp2f(Sv[kg][3]);
        rs += (e0 + e1) + (e2 + e3);
        union { bf16x4 v; unsigned int u[2]; } pu;
        pu.u[0] = cvtpk(e0, e1);
        pu.u[1] = cvtpk(e2, e3);
        pf[st][kg] = pu.v;
      }
      ls[st] = rs;
    }

    // PV: V fragments read ONCE per dg, used by both strips
    __builtin_amdgcn_s_setprio(1);
#pragma unroll
    for (int dg = 0; dg < 4; ++dg) {
      bf16x4 vf[4];
#pragma unroll
      for (int kg = 0; kg < 4; ++kg)
        vf[kg] = *(const bf16x4*)&Vs[p][(dg * 16 + lr) * 64 +
                                        (((kg * 2 + (quad >> 1)) ^ (lr & 7)) * 8) +
                                        (((quad & 1) ^ ((lr >> 3) & 1)) * 4)];
#pragma unroll
      for (int st = 0; st < 2; ++st) {
        if (!act[st]) continue;
#pragma unroll
        for (int kg = 0; kg < 4; ++kg)
          Ot[st][dg] = MFMA1616(vf[kg], pf[st][kg], Ot[st][dg]);
      }
    }
    __builtin_amdgcn_s_setprio(0);
  }

#pragma unroll
  for (int st = 0; st < 2; ++st) {
    ls[st] += __shfl_xor(ls[st], 16);
    ls[st] += __shfl_xor(ls[st], 32);
  }

  if (T < 8) {
    // single-chunk block: finalize and write AO (rows < 1024 of this bh)
#pragma unroll
    for (int st = 0; st < 2; ++st) {
      const float rl = __builtin_amdgcn_rcpf(ls[st]);
      const int s = R0 + st * 16 + lr;
#pragma unroll
      for (int dg = 0; dg < 4; ++dg) {
        const size_t o = ((size_t)b * S_LEN + s) * D_MODEL + h * 64 + dg * 16 + quad * 4;
        *(unsigned int*)&AO[o]     = cvtpk(Ot[st][dg][0] * rl, Ot[st][dg][1] * rl);
        *(unsigned int*)&AO[o + 2] = cvtpk(Ot[st][dg][2] * rl, Ot[st][dg][3] * rl);
      }
    }
  } else {
    // split block: write f32 partials (m=0, l, unnormalized O); k_combine merges.
#pragma unroll
    for (int st = 0; st < 2; ++st) {
      const int sL = T * 8 + wid * 2 + st;      // global strip 64..127
      float* P = Pp + ((size_t)((bh * 64 + (sL - 64)) * 2 + c)) * (16 * 68) + lr * 68;
#pragma unroll
      for (int dg = 0; dg < 4; ++dg)
        *(f32x4*)&P[dg * 16 + quad * 4] = Ot[st][dg];
      if (quad == 0) { P[64] = 0.f; P[65] = ls[st]; }
    }
  }
}

// ---------------- combine: merge the 2 partials of each split strip ----------------
__global__ __launch_bounds__(256) void k_combine(const float* __restrict__ Pp,
                                                 unsigned short* __restrict__ AO) {
  const int lane = threadIdx.x & 63;
  const int sid = blockIdx.x * 4 + (threadIdx.x >> 6);   // 0..2047
  const int bh = sid >> 6, jrel = sid & 63;
  const int b = bh >> 4, h = bh & 15;
  const int r = lane & 15, cg = lane >> 4;
  const float* P0 = Pp + ((size_t)(bh * 64 + jrel) * 2) * (16 * 68) + r * 68;
  const float* P1 = P0 + 16 * 68;
  const float m0 = P0[64], l0 = P0[65];
  const float m1 = P1[64], l1 = P1[65];
  const float M = fmaxf(m0, m1);
  const float w0 = __builtin_amdgcn_exp2f(m0 - M);
  const float w1 = __builtin_amdgcn_exp2f(m1 - M);
  const float rl = __builtin_amdgcn_rcpf(l0 * w0 + l1 * w1);
  const int s = (64 + jrel) * 16 + r;                    // rows 1024..2047
  const size_t o0 = ((size_t)b * S_LEN + s) * D_MODEL + h * 64 + cg * 16;
#pragma unroll
  for (int q4 = 0; q4 < 4; ++q4) {
    f32x4 a = *(const f32x4*)&P0[cg * 16 + q4 * 4];
    f32x4 b4 = *(const f32x4*)&P1[cg * 16 + q4 * 4];
    float o0v = (a[0] * w0 + b4[0] * w1) * rl;
    float o1v = (a[1] * w0 + b4[1] * w1) * rl;
    float o2v = (a[2] * w0 + b4[2] * w1) * rl;
    float o3v = (a[3] * w0 + b4[3] * w1) * rl;
    *(unsigned int*)&AO[o0 + q4 * 4]     = cvtpk(o0v, o1v);
    *(unsigned int*)&AO[o0 + q4 * 4 + 2] = cvtpk(o2v, o3v);
  }
}

extern "C" void kernel_launch(void* const* d_in, const int* in_sizes, int n_in,
                              void* d_out, int out_size, void* d_ws, size_t ws_size,
                              hipStream_t stream) {
  const float* x      = (const float*)d_in[0];
  const float* w_attn = (const float*)d_in[1];
  const float* b_attn = (const float*)d_in[2];
  const float* w_proj = (const float*)d_in[3];
  const float* b_proj = (const float*)d_in[4];
  float* out = (float*)d_out;

  unsigned short* ws     = (unsigned short*)d_ws;
  unsigned short* xb     = ws;                                   // 4096x1024
  unsigned short* wqkvT  = xb + (size_t)M_ROWS * D_MODEL;        // 3072x1024
  unsigned short* wprojT = wqkvT + (size_t)N_QKV * D_MODEL;      // 1024x1024
  unsigned short* Qb     = wprojT + (size_t)D_MODEL * D_MODEL;   // [B*H, S, hd] (pre-scaled)
  unsigned short* Kb     = Qb + (size_t)M_ROWS * D_MODEL;        // [B*H, S, hd]
  unsigned short* VT     = Kb + (size_t)M_ROWS * D_MODEL;        // [B*H, hd, S] (half-swapped)
  float* Pp              = (float*)(VT + (size_t)M_ROWS * D_MODEL); // split-K partials, 17.8MB
  unsigned short* AO     = xb;  // reuse: xb dead after QKV GEMM

  k_prep<<<6144, 256, 0, stream>>>(x, xb, w_attn, wqkvT, w_proj, wprojT);
  k_gemm_qkv<<<768, 256, 0, stream>>>(xb, wqkvT, b_attn, Qb, Kb, VT);
  k_attn19<<<768, 256, 0, stream>>>(Qb, Kb, VT, AO, Pp);
  k_combine<<<512, 256, 0, stream>>>(Pp, AO);
  k_gemm_proj<<<256, 256, 0, stream>>>(AO, wprojT, b_proj, out);
}